// Round 13
// baseline (487.766 us; speedup 1.0000x reference)
//
#include <hip/hip_runtime.h>
#include <cstddef>
#include <cstdint>

#define NNODES 50000
#define NEDGES 800000
#define FDIM   256

#define SCAN_BLOCKS 256
#define SCAN_CHUNK  ((NNODES + SCAN_BLOCKS - 1) / SCAN_BLOCKS)   // 196

typedef __attribute__((ext_vector_type(8))) _Float16 f16x8;
typedef __attribute__((ext_vector_type(8))) unsigned short ushort8;
typedef __attribute__((ext_vector_type(4))) float f32x4;

__device__ __forceinline__ float leaky_exp(float a) {
    float e = a > 0.f ? a : 0.2f * a;
    return __expf(e);
}
__device__ __forceinline__ unsigned short f2h(float f) {
    return __builtin_bit_cast(unsigned short, (_Float16)f);
}
__device__ __forceinline__ float hlo(uint32_t u) {
    _Float16 h = __builtin_bit_cast(_Float16, (unsigned short)(u & 0xffffu));
    return (float)h;
}
__device__ __forceinline__ float hhi(uint32_t u) {
    _Float16 h = __builtin_bit_cast(_Float16, (unsigned short)(u >> 16));
    return (float)h;
}

// --- W[256][256] -> Wt[n][k] f16 (transpose + convert); blockIdx.y picks W1/W2 ---
__global__ __launch_bounds__(256) void wprep_k(const float* __restrict__ W1,
                                               unsigned short* __restrict__ Wt1,
                                               const float* __restrict__ W2,
                                               unsigned short* __restrict__ Wt2) {
    const float* W = blockIdx.y ? W2 : W1;
    unsigned short* Wt = blockIdx.y ? Wt2 : Wt1;
    int n = blockIdx.x, k = threadIdx.x;
    Wt[n * 256 + k] = f2h(W[k * 256 + n]);
}

// --------- f16 MFMA GEMM -> SLICED C layout [8][N][32] f16 ---------
// AMODE 0: A fp32 row-major (layer 1). AMODE 1: A f16 sliced (layer 2, = h1).
// FUSE_LOGITS (grid.y=2, H=4): per-row per-head logits from f32 accumulators.
template <int AMODE, bool FUSE_LOGITS>
__global__ __launch_bounds__(256) void gemm_mfma(const void* __restrict__ Aab,
                                                 const unsigned short* __restrict__ Bt,
                                                 unsigned short* __restrict__ C,
                                                 const float* __restrict__ atts,
                                                 const float* __restrict__ attd,
                                                 float* __restrict__ as_,
                                                 float* __restrict__ ad_,
                                                 int M) {
    __shared__ unsigned short As[128 * 64];
    __shared__ unsigned short Bs[128 * 64];
    const int t = threadIdx.x;
    const int lane = t & 63, wid = t >> 6;
    const int wr = wid >> 1, wc = wid & 1;
    const int bm = blockIdx.x * 128;
    const int bny = blockIdx.y;
    const int bn = bny * 128;
    f32x4 acc[4][4] = {};
    const int lrow = t >> 3, lslot = t & 7;
    for (int k0 = 0; k0 < 256; k0 += 64) {
        __syncthreads();
#pragma unroll
        for (int i = 0; i < 4; ++i) {
            int row = lrow + 32 * i;
            int ga = bm + row; ga = ga < M ? ga : M - 1;
            if (AMODE == 0) {
                const float* p = (const float*)Aab + (size_t)ga * FDIM + k0 + lslot * 8;
                float4 f0 = *(const float4*)p;
                float4 f1 = *(const float4*)(p + 4);
                ushort8 r;
                r[0] = f2h(f0.x); r[1] = f2h(f0.y); r[2] = f2h(f0.z); r[3] = f2h(f0.w);
                r[4] = f2h(f1.x); r[5] = f2h(f1.y); r[6] = f2h(f1.z); r[7] = f2h(f1.w);
                *(ushort8*)(As + row * 64 + ((lslot ^ (row & 7)) << 3)) = r;
            } else {
                const unsigned short* A16 = (const unsigned short*)Aab;
                int k = k0 + lslot * 8;
                uint4 av = *(const uint4*)(A16 +
                    ((size_t)(k >> 5) * NNODES + ga) * 32 + (k & 31));
                *(uint4*)(As + row * 64 + ((lslot ^ (row & 7)) << 3)) = av;
            }
            uint4 bv = *(const uint4*)(Bt + (size_t)(bn + row) * FDIM + k0 + lslot * 8);
            *(uint4*)(Bs + row * 64 + ((lslot ^ (row & 7)) << 3)) = bv;
        }
        __syncthreads();
#pragma unroll
        for (int ks = 0; ks < 2; ++ks) {
            const int kq = ks * 4 + (lane >> 4);
            f16x8 a[4], b[4];
#pragma unroll
            for (int f = 0; f < 4; ++f) {
                int ra = wr * 64 + f * 16 + (lane & 15);
                a[f] = *(const f16x8*)(As + ra * 64 + ((kq ^ (ra & 7)) << 3));
                int rb = wc * 64 + f * 16 + (lane & 15);
                b[f] = *(const f16x8*)(Bs + rb * 64 + ((kq ^ (rb & 7)) << 3));
            }
#pragma unroll
            for (int mf = 0; mf < 4; ++mf)
#pragma unroll
                for (int nf = 0; nf < 4; ++nf)
                    acc[mf][nf] = __builtin_amdgcn_mfma_f32_16x16x32_f16(
                        a[mf], b[nf], acc[mf][nf], 0, 0, 0);
        }
    }
    const int col0 = bn + wc * 64 + (lane & 15);
    const int row00 = bm + wr * 64 + (lane >> 4) * 4;
    if (FUSE_LOGITS) {
        const int head = 2 * bny + wc;
        float sv4[4], dv4[4];
#pragma unroll
        for (int nf = 0; nf < 4; ++nf) {
            sv4[nf] = atts[col0 + nf * 16];
            dv4[nf] = attd[col0 + nf * 16];
        }
#pragma unroll
        for (int mf = 0; mf < 4; ++mf)
#pragma unroll
            for (int r = 0; r < 4; ++r) {
                float ps = 0.f, pd = 0.f;
#pragma unroll
                for (int nf = 0; nf < 4; ++nf) {
                    float v = acc[mf][nf][r];
                    ps = fmaf(v, sv4[nf], ps);
                    pd = fmaf(v, dv4[nf], pd);
                }
#pragma unroll
                for (int off = 1; off < 16; off <<= 1) {
                    ps += __shfl_xor(ps, off);
                    pd += __shfl_xor(pd, off);
                }
                int row = row00 + mf * 16 + r;
                if ((lane & 15) == 0 && row < M) {
                    as_[row * 4 + head] = ps;
                    ad_[row * 4 + head] = pd;
                }
            }
    }
    // ---- C store to sliced layout ----
#pragma unroll
    for (int mf = 0; mf < 4; ++mf)
#pragma unroll
        for (int nf = 0; nf < 4; ++nf) {
            f32x4 v = acc[mf][nf];
            int colb = bn + wc * 64 + nf * 16;            // 16-aligned
            size_t base = (size_t)(colb >> 5) * NNODES * 32 + (colb & 31) + (lane & 15);
#pragma unroll
            for (int r = 0; r < 4; ++r) {
                int row = row00 + mf * 16 + r;
                if (row < M) C[base + (size_t)row * 32] = f2h(v[r]);
            }
        }
}

// ------- layer-2 attention logits from sliced f16 xp; wave per node -------
__global__ __launch_bounds__(256) void aprep1_k(const unsigned short* __restrict__ xp_s,
                                                const float* __restrict__ atts,
                                                const float* __restrict__ attd,
                                                float* __restrict__ as_,
                                                float* __restrict__ ad_) {
    const int lane = threadIdx.x & 63;
    const int n = blockIdx.x * 4 + (threadIdx.x >> 6);
    if (n >= NNODES) return;
    const int c = lane << 2;
    uint2 u = *(const uint2*)(xp_s + ((size_t)(c >> 5) * NNODES + n) * 32 + (c & 31));
    float v0 = hlo(u.x), v1 = hhi(u.x), v2 = hlo(u.y), v3 = hhi(u.y);
    float4 s4 = *(const float4*)(atts + c);
    float4 d4 = *(const float4*)(attd + c);
    float ss = v0 * s4.x + v1 * s4.y + v2 * s4.z + v3 * s4.w;
    float sd = v0 * d4.x + v1 * d4.y + v2 * d4.z + v3 * d4.w;
#pragma unroll
    for (int off = 1; off < 64; off <<= 1) {
        ss += __shfl_xor(ss, off);
        sd += __shfl_xor(sd, off);
    }
    if (lane == 0) { as_[n] = ss; ad_[n] = sd; }
}

// ---------------- CSR build: histogram -> 3-phase scan -> scatter ----------------
__global__ __launch_bounds__(256) void hist_k(const int* __restrict__ ei,
                                              int* __restrict__ deg) {
    int e = blockIdx.x * 256 + threadIdx.x;
    if (e < NEDGES) atomicAdd(&deg[ei[NEDGES + e]], 1);
}

__global__ __launch_bounds__(256) void scanA_k(const int* __restrict__ deg,
                                               int* __restrict__ bsum) {
    const int b = blockIdx.x, t = threadIdx.x;
    const int i = b * SCAN_CHUNK + t;
    int v = (t < SCAN_CHUNK && i < NNODES) ? deg[i] : 0;
#pragma unroll
    for (int off = 1; off < 64; off <<= 1) v += __shfl_xor(v, off);
    __shared__ int ws[4];
    if ((t & 63) == 0) ws[t >> 6] = v;
    __syncthreads();
    if (t == 0) bsum[b] = ws[0] + ws[1] + ws[2] + ws[3];
}

__global__ __launch_bounds__(256) void scanB_k(const int* __restrict__ bsum,
                                               int* __restrict__ boff,
                                               int* __restrict__ rowptr) {
    const int t = threadIdx.x;
    const int lane = t & 63, wid = t >> 6;
    int orig = bsum[t];
    int v = orig;
#pragma unroll
    for (int off = 1; off < 64; off <<= 1) {
        int u = __shfl_up(v, off);
        if (lane >= off) v += u;
    }
    __shared__ int ws[4], wo[4];
    if (lane == 63) ws[wid] = v;
    __syncthreads();
    if (t == 0) {
        int a = 0;
        for (int k = 0; k < 4; ++k) { wo[k] = a; a += ws[k]; }
        rowptr[NNODES] = a;
    }
    __syncthreads();
    boff[t] = wo[wid] + v - orig;
}

__global__ __launch_bounds__(256) void scanC_k(const int* __restrict__ deg,
                                               const int* __restrict__ boff,
                                               int* __restrict__ rowptr) {
    const int b = blockIdx.x, t = threadIdx.x;
    const int i = b * SCAN_CHUNK + t;
    const bool ok = (t < SCAN_CHUNK && i < NNODES);
    int orig = ok ? deg[i] : 0;
    int v = orig;
    const int lane = t & 63, wid = t >> 6;
#pragma unroll
    for (int off = 1; off < 64; off <<= 1) {
        int u = __shfl_up(v, off);
        if (lane >= off) v += u;
    }
    __shared__ int ws[4], wo[4];
    if (lane == 63) ws[wid] = v;
    __syncthreads();
    if (t == 0) {
        int a = 0;
        for (int k = 0; k < 4; ++k) { wo[k] = a; a += ws[k]; }
    }
    __syncthreads();
    if (ok) rowptr[i] = boff[b] + wo[wid] + v - orig;
}

__global__ __launch_bounds__(256) void scatter_k(const int* __restrict__ ei,
                                                 const int* __restrict__ rowptr,
                                                 int* __restrict__ deg,
                                                 int* __restrict__ ssrc) {
    int e = blockIdx.x * 256 + threadIdx.x;
    if (e >= NEDGES) return;
    int s = ei[e], d = ei[NEDGES + e];
    int old = atomicSub(&deg[d], 1);
    ssrc[rowptr[d + 1] - old] = s;
}

// ---- layer-1 weight precompute: wave/node; wbuf head-major [4][E]; den incl self ----
__global__ __launch_bounds__(256) void wk1_k(const float* __restrict__ as_,
                                             const float* __restrict__ ad_,
                                             const int* __restrict__ rowptr,
                                             const int* __restrict__ ssrc,
                                             float* __restrict__ wbuf,
                                             float* __restrict__ den,
                                             float* __restrict__ wself) {
    const int lane = threadIdx.x & 63;
    const int n = blockIdx.x * 4 + (threadIdx.x >> 6);
    if (n >= NNODES) return;
    float4 ad4 = *(const float4*)(ad_ + (size_t)n * 4);
    float d0 = 0.f, d1 = 0.f, d2 = 0.f, d3 = 0.f;
    const int beg = rowptr[n], end = rowptr[n + 1];
    for (int base = beg; base < end; base += 64) {
        int e = base + lane;
        float w0 = 0.f, w1 = 0.f, w2 = 0.f, w3 = 0.f;
        if (e < end) {
            int sv = ssrc[e];
            float4 a4 = *(const float4*)(as_ + (size_t)sv * 4);
            w0 = leaky_exp(a4.x + ad4.x);
            w1 = leaky_exp(a4.y + ad4.y);
            w2 = leaky_exp(a4.z + ad4.z);
            w3 = leaky_exp(a4.w + ad4.w);
            wbuf[0 * NEDGES + e] = w0;
            wbuf[1 * NEDGES + e] = w1;
            wbuf[2 * NEDGES + e] = w2;
            wbuf[3 * NEDGES + e] = w3;
        }
        d0 += w0; d1 += w1; d2 += w2; d3 += w3;
    }
#pragma unroll
    for (int off = 1; off < 64; off <<= 1) {
        d0 += __shfl_xor(d0, off);
        d1 += __shfl_xor(d1, off);
        d2 += __shfl_xor(d2, off);
        d3 += __shfl_xor(d3, off);
    }
    if (lane == 0) {
        float4 a4 = *(const float4*)(as_ + (size_t)n * 4);
        float s0 = leaky_exp(a4.x + ad4.x), s1 = leaky_exp(a4.y + ad4.y);
        float s2 = leaky_exp(a4.z + ad4.z), s3 = leaky_exp(a4.w + ad4.w);
        wself[n * 4 + 0] = s0; wself[n * 4 + 1] = s1;
        wself[n * 4 + 2] = s2; wself[n * 4 + 3] = s3;
        den[n * 4 + 0] = d0 + s0; den[n * 4 + 1] = d1 + s1;
        den[n * 4 + 2] = d2 + s2; den[n * 4 + 3] = d3 + s3;
    }
}

// ---- layer-2 weight precompute (H=1) ----
__global__ __launch_bounds__(256) void wk2_k(const float* __restrict__ as_,
                                             const float* __restrict__ ad_,
                                             const int* __restrict__ rowptr,
                                             const int* __restrict__ ssrc,
                                             float* __restrict__ wbuf,
                                             float* __restrict__ den,
                                             float* __restrict__ wself) {
    const int lane = threadIdx.x & 63;
    const int n = blockIdx.x * 4 + (threadIdx.x >> 6);
    if (n >= NNODES) return;
    const float adn = ad_[n];
    float d = 0.f;
    const int beg = rowptr[n], end = rowptr[n + 1];
    for (int base = beg; base < end; base += 64) {
        int e = base + lane;
        float w = 0.f;
        if (e < end) {
            int sv = ssrc[e];
            w = leaky_exp(as_[sv] + adn);
            wbuf[e] = w;
        }
        d += w;
    }
#pragma unroll
    for (int off = 1; off < 64; off <<= 1) d += __shfl_xor(d, off);
    if (lane == 0) {
        float s = leaky_exp(as_[n] + adn);
        wself[n] = s;
        den[n] = d + s;
    }
}

// ---- layer-1 sliced gather: grid (nodeblk, 8); slice s (32 feats) L2-resident ----
__global__ __launch_bounds__(256) void g1s_k(const unsigned short* __restrict__ xp_s,
                                             const float* __restrict__ wbuf,
                                             const float* __restrict__ den,
                                             const float* __restrict__ wself,
                                             const int* __restrict__ rowptr,
                                             const int* __restrict__ ssrc,
                                             const float* __restrict__ bias,
                                             unsigned short* __restrict__ h1_s) {
    const int lane = threadIdx.x & 63;
    const int n = blockIdx.x * 4 + (threadIdx.x >> 6);
    if (n >= NNODES) return;
    const int s = blockIdx.y;
    const int h = s >> 1;
    const int g = lane >> 4;          // edge sub-group 0..3
    const int fl = lane & 15;         // feature pair lane
    const unsigned short* xs = xp_s + (size_t)s * NNODES * 32;
    const float* wb = wbuf + (size_t)h * NEDGES;
    float a0 = 0.f, a1 = 0.f;
    const int beg = rowptr[n], end = rowptr[n + 1];
    for (int base = beg; base < end; base += 64) {
        int e = base + lane;
        int sv = 0; float wv = 0.f;
        if (e < end) { sv = ssrc[e]; wv = wb[e]; }
        const int cnt = min(64, end - base);
        int i = 0;
        for (; i + 8 <= cnt; i += 8) {
            int i0 = i + g, i1 = i + 4 + g;
            int s0 = __shfl(sv, i0), s1b = __shfl(sv, i1);
            float w0 = __shfl(wv, i0), w1 = __shfl(wv, i1);
            uint32_t u0 = *(const uint32_t*)(xs + (size_t)s0 * 32 + fl * 2);
            uint32_t u1 = *(const uint32_t*)(xs + (size_t)s1b * 32 + fl * 2);
            a0 = fmaf(hlo(u0), w0, a0); a1 = fmaf(hhi(u0), w0, a1);
            a0 = fmaf(hlo(u1), w1, a0); a1 = fmaf(hhi(u1), w1, a1);
        }
        for (; i < cnt; i += 4) {       // uniform tail: shfl on all lanes
            int idx = i + g;
            int s0 = __shfl(sv, idx);
            float w0 = __shfl(wv, idx);
            if (idx < cnt) {
                uint32_t u0 = *(const uint32_t*)(xs + (size_t)s0 * 32 + fl * 2);
                a0 = fmaf(hlo(u0), w0, a0); a1 = fmaf(hhi(u0), w0, a1);
            }
        }
    }
    // merge the 4 edge sub-groups
    a0 += __shfl_xor(a0, 16); a0 += __shfl_xor(a0, 32);
    a1 += __shfl_xor(a1, 16); a1 += __shfl_xor(a1, 32);
    if (lane < 16) {
        float w = wself[n * 4 + h];
        uint32_t u = *(const uint32_t*)(xs + (size_t)n * 32 + fl * 2);
        a0 = fmaf(hlo(u), w, a0); a1 = fmaf(hhi(u), w, a1);
        float inv = 1.f / (den[n * 4 + h] + 1e-16f);
        int c = s * 32 + fl * 2;
        float o0 = a0 * inv + bias[c];
        float o1 = a1 * inv + bias[c + 1];
        o0 = o0 > 0.f ? o0 : __expf(o0) - 1.f;
        o1 = o1 > 0.f ? o1 : __expf(o1) - 1.f;
        uint32_t r = (uint32_t)f2h(o0) | ((uint32_t)f2h(o1) << 16);
        *(uint32_t*)(h1_s + ((size_t)s * NNODES + n) * 32 + fl * 2) = r;
    }
}

// ---- layer-2 sliced gather + bias + ELU + BN; f16 sliced out (pre-LN) ----
__global__ __launch_bounds__(256) void g2s_k(const unsigned short* __restrict__ xp_s,
                                             const float* __restrict__ wbuf,
                                             const float* __restrict__ den,
                                             const float* __restrict__ wself,
                                             const int* __restrict__ rowptr,
                                             const int* __restrict__ ssrc,
                                             const float* __restrict__ bias,
                                             const float* __restrict__ bng,
                                             const float* __restrict__ bnb,
                                             const float* __restrict__ bnm,
                                             const float* __restrict__ bnv,
                                             unsigned short* __restrict__ acc_s) {
    const int lane = threadIdx.x & 63;
    const int n = blockIdx.x * 4 + (threadIdx.x >> 6);
    if (n >= NNODES) return;
    const int s = blockIdx.y;
    const int g = lane >> 4;
    const int fl = lane & 15;
    const unsigned short* xs = xp_s + (size_t)s * NNODES * 32;
    float a0 = 0.f, a1 = 0.f;
    const int beg = rowptr[n], end = rowptr[n + 1];
    for (int base = beg; base < end; base += 64) {
        int e = base + lane;
        int sv = 0; float wv = 0.f;
        if (e < end) { sv = ssrc[e]; wv = wbuf[e]; }
        const int cnt = min(64, end - base);
        int i = 0;
        for (; i + 8 <= cnt; i += 8) {
            int i0 = i + g, i1 = i + 4 + g;
            int s0 = __shfl(sv, i0), s1b = __shfl(sv, i1);
            float w0 = __shfl(wv, i0), w1 = __shfl(wv, i1);
            uint32_t u0 = *(const uint32_t*)(xs + (size_t)s0 * 32 + fl * 2);
            uint32_t u1 = *(const uint32_t*)(xs + (size_t)s1b * 32 + fl * 2);
            a0 = fmaf(hlo(u0), w0, a0); a1 = fmaf(hhi(u0), w0, a1);
            a0 = fmaf(hlo(u1), w1, a0); a1 = fmaf(hhi(u1), w1, a1);
        }
        for (; i < cnt; i += 4) {
            int idx = i + g;
            int s0 = __shfl(sv, idx);
            float w0 = __shfl(wv, idx);
            if (idx < cnt) {
                uint32_t u0 = *(const uint32_t*)(xs + (size_t)s0 * 32 + fl * 2);
                a0 = fmaf(hlo(u0), w0, a0); a1 = fmaf(hhi(u0), w0, a1);
            }
        }
    }
    a0 += __shfl_xor(a0, 16); a0 += __shfl_xor(a0, 32);
    a1 += __shfl_xor(a1, 16); a1 += __shfl_xor(a1, 32);
    if (lane < 16) {
        float w = wself[n];
        uint32_t u = *(const uint32_t*)(xs + (size_t)n * 32 + fl * 2);
        a0 = fmaf(hlo(u), w, a0); a1 = fmaf(hhi(u), w, a1);
        float inv = 1.f / (den[n] + 1e-16f);
        int c = s * 32 + fl * 2;
        float o0 = a0 * inv + bias[c];
        float o1 = a1 * inv + bias[c + 1];
        o0 = o0 > 0.f ? o0 : __expf(o0) - 1.f;                      // ELU
        o1 = o1 > 0.f ? o1 : __expf(o1) - 1.f;
        o0 = (o0 - bnm[c]) * rsqrtf(bnv[c] + 1e-5f) * bng[c] + bnb[c];          // BN
        o1 = (o1 - bnm[c + 1]) * rsqrtf(bnv[c + 1] + 1e-5f) * bng[c + 1] + bnb[c + 1];
        uint32_t r = (uint32_t)f2h(o0) | ((uint32_t)f2h(o1) << 16);
        *(uint32_t*)(acc_s + ((size_t)s * NNODES + n) * 32 + fl * 2) = r;
    }
}

// ---- finalize: LayerNorm over full row from sliced f16; write fp32 out ----
__global__ __launch_bounds__(256) void fin_k(const unsigned short* __restrict__ acc_s,
                                             const float* __restrict__ lng,
                                             const float* __restrict__ lnb,
                                             float* __restrict__ out) {
    const int lane = threadIdx.x & 63;
    const int n = blockIdx.x * 4 + (threadIdx.x >> 6);
    if (n >= NNODES) return;
    const int c = lane << 2;
    uint2 u = *(const uint2*)(acc_s + ((size_t)(c >> 5) * NNODES + n) * 32 + (c & 31));
    float v0 = hlo(u.x), v1 = hhi(u.x), v2 = hlo(u.y), v3 = hhi(u.y);
    float s1 = v0 + v1 + v2 + v3;
    float s2 = v0 * v0 + v1 * v1 + v2 * v2 + v3 * v3;
#pragma unroll
    for (int off = 1; off < 64; off <<= 1) {
        s1 += __shfl_xor(s1, off);
        s2 += __shfl_xor(s2, off);
    }
    float mu  = s1 * (1.f / 256.f);
    float var = s2 * (1.f / 256.f) - mu * mu;
    float r   = rsqrtf(var + 1e-5f);
    float4 lg = *(const float4*)(lng + c);
    float4 lb = *(const float4*)(lnb + c);
    float4 o;
    o.x = (v0 - mu) * r * lg.x + lb.x;
    o.y = (v1 - mu) * r * lg.y + lb.y;
    o.z = (v2 - mu) * r * lg.z + lb.z;
    o.w = (v3 - mu) * r * lg.w + lb.w;
    *(float4*)(out + (size_t)n * FDIM + c) = o;
}

extern "C" void kernel_launch(void* const* d_in, const int* in_sizes, int n_in,
                              void* d_out, int out_size, void* d_ws, size_t ws_size,
                              hipStream_t stream) {
    const float* x      = (const float*)d_in[0];
    const int*   ei     = (const int*)d_in[1];
    const float* W1     = (const float*)d_in[2];
    const float* atts1  = (const float*)d_in[3];
    const float* attd1  = (const float*)d_in[4];
    const float* bias1  = (const float*)d_in[5];
    const float* W2     = (const float*)d_in[6];
    const float* atts2  = (const float*)d_in[7];
    const float* attd2  = (const float*)d_in[8];
    const float* bias2  = (const float*)d_in[9];
    const float* bng    = (const float*)d_in[10];
    const float* bnb    = (const float*)d_in[11];
    const float* bnm    = (const float*)d_in[12];
    const float* bnv    = (const float*)d_in[13];
    const float* lng    = (const float*)d_in[14];
    const float* lnb    = (const float*)d_in[15];

    const size_t NF = (size_t)NNODES * FDIM;
    // ---- workspace ----
    unsigned short* xp_s   = (unsigned short*)d_ws;       // 25.6 MB (xp sliced, both layers)
    unsigned short* h1a_s  = xp_s + NF;                   // 25.6 MB (h1 sliced, then acc2 sliced)
    unsigned short* wt1    = h1a_s + NF;
    unsigned short* wt2    = wt1 + 65536;
    float* as1    = (float*)(wt2 + 65536);                // N*4
    float* ad1    = as1 + (size_t)NNODES * 4;             // N*4
    float* as2    = ad1 + (size_t)NNODES * 4;             // N
    float* ad2    = as2 + NNODES;                         // N
    float* den2   = ad2 + NNODES;                         // N
    float* wself2 = den2 + NNODES;                        // N
    float* wbuf2  = wself2 + NNODES;                      // E
    int*   deg    = (int*)(wbuf2 + NEDGES);
    int*   rowptr = deg + NNODES;
    int*   bsum   = rowptr + (NNODES + 1);
    int*   boff   = bsum + SCAN_BLOCKS;
    int*   ssrc   = boff + SCAN_BLOCKS;                   // E
    // ---- scratch in d_out (dead until fin_k) ----
    float* wbuf1  = (float*)d_out;                        // 4*E = 12.8 MB
    float* den1   = wbuf1 + (size_t)4 * NEDGES;           // N*4
    float* wself1 = den1 + (size_t)NNODES * 4;            // N*4
    float* outf   = (float*)d_out;

    const dim3 gemm_grid((NNODES + 127) / 128, 2);
    const int node_wave_blocks = (NNODES + 3) / 4;
    const dim3 slice_grid(node_wave_blocks, 8);
    const int edge_thread_blocks = (NEDGES + 255) / 256;

    // ---- prep: W transpose/convert + CSR ----
    wprep_k<<<dim3(256, 2), 256, 0, stream>>>(W1, wt1, W2, wt2);
    hipMemsetAsync(deg, 0, NNODES * sizeof(int), stream);
    hist_k<<<edge_thread_blocks, 256, 0, stream>>>(ei, deg);
    scanA_k<<<SCAN_BLOCKS, 256, 0, stream>>>(deg, bsum);
    scanB_k<<<1, 256, 0, stream>>>(bsum, boff, rowptr);
    scanC_k<<<SCAN_BLOCKS, 256, 0, stream>>>(deg, boff, rowptr);
    scatter_k<<<edge_thread_blocks, 256, 0, stream>>>(ei, rowptr, deg, ssrc);

    // ---- layer 1 ----
    gemm_mfma<0, true><<<gemm_grid, 256, 0, stream>>>(
        x, wt1, xp_s, atts1, attd1, as1, ad1, NNODES);
    wk1_k<<<node_wave_blocks, 256, 0, stream>>>(as1, ad1, rowptr, ssrc,
                                                wbuf1, den1, wself1);
    g1s_k<<<slice_grid, 256, 0, stream>>>(xp_s, wbuf1, den1, wself1,
                                          rowptr, ssrc, bias1, h1a_s);

    // ---- layer 2 ----
    gemm_mfma<1, false><<<gemm_grid, 256, 0, stream>>>(
        h1a_s, wt2, xp_s, nullptr, nullptr, nullptr, nullptr, NNODES);
    aprep1_k<<<node_wave_blocks, 256, 0, stream>>>(xp_s, atts2, attd2, as2, ad2);
    wk2_k<<<node_wave_blocks, 256, 0, stream>>>(as2, ad2, rowptr, ssrc,
                                                wbuf2, den2, wself2);
    g2s_k<<<slice_grid, 256, 0, stream>>>(xp_s, wbuf2, den2, wself2,
                                          rowptr, ssrc, bias2,
                                          bng, bnb, bnm, bnv, h1a_s /*acc_s*/);
    fin_k<<<node_wave_blocks, 256, 0, stream>>>(h1a_s, lng, lnb, outf);
}